// Round 21
// baseline (34.715 us; speedup 1.0000x reference)
//
#include <hip/hip_runtime.h>

#define NPERS 64
#define NJOINT 15
#define NDEPTH 128
#define BIGF 100000.0f
#define EPSF 1e-8f
#define INFF 3.0e38f

// R20 post-mortem closed the model: uniform ds_read_b128 still costs ~12cyc
// of LDS pipe (R2=38us, R18-marginal=14.4us, R19/R20 all fit). The loop was
// LDS-instruction-bound. This round: coefficients move to the SCALAR path.
//  - coef_kernel folds (w,wx,wy,c) ONCE per batch into d_ws (kills the 64x
//    duplicated fold too);
//  - in the main loop every coef address is built from {blockIdx,
//    readfirstlane(wv), compile-time j,g} only -> provably scalar ->
//    s_load_dwordx4 into SGPRs, compiler-scheduled (no per-q asm waits:
//    that was R6's mistake). Loop LDS instr count -> ZERO.
//  - single __syncthreads (sq staging + bvred share the post-argmin barrier).
// fp order identical to R20 (absmax lineage 9.5e-7).

// ---------------- coef kernel: one thread per (b,q) ----------------
// layout in ws: gco[b][j][192]  (192 floats per (b,j): q*3 -> w,wx,wy)
//               gc [b][q]       (c term), offset B*15*192
__global__ __launch_bounds__(256) void coef_kernel(
    const float* __restrict__ p2d,   // (B,NP,NJ,2)
    const float* __restrict__ vis,   // (B,NP,NJ)
    float* __restrict__ ws,
    int total)                       // B*NPERS
{
    int t = blockIdx.x * 256 + threadIdx.x;
    if (t >= total) return;
    const int b = t >> 6, q = t & 63;
    float v[NJOINT], rx[NJOINT], ry[NJOINT];
    float vs = 0.0f, t2 = 0.0f;
    #pragma unroll
    for (int j = 0; j < NJOINT; ++j) {
        v[j]  = vis[t * NJOINT + j];
        rx[j] = p2d[(t * NJOINT + j) * 2 + 0];
        ry[j] = p2d[(t * NJOINT + j) * 2 + 1];
        vs += v[j];
        t2 = fmaf(rx[j] * rx[j] + ry[j] * ry[j], v[j], t2);
    }
    float inv = 1.0f / (vs + EPSF);
    float* gco = ws + (size_t)b * NJOINT * 192;
    #pragma unroll
    for (int j = 0; j < NJOINT; ++j) {
        gco[j * 192 + q * 3 + 0] = v[j] * inv;
        gco[j * 192 + q * 3 + 1] = 2.0f * v[j] * rx[j] * inv;
        gco[j * 192 + q * 3 + 2] = 2.0f * v[j] * ry[j] * inv;
    }
    ws[(size_t)16 * NJOINT * 192 + b * NPERS + q] = t2 * inv;   // c term
}

// ---------------- main kernel ----------------
__global__ __launch_bounds__(256, 4)
void pose_match_kernel(
    const float* __restrict__ poses_3d,   // (B,NP,NJ,ND,3)
    const float* __restrict__ p2d,        // (B,NP,NJ,2)
    const float* __restrict__ vis,        // (B,NP,NJ)
    const int*   __restrict__ nper,       // (B,)
    const float* __restrict__ Rm,         // (B,3,3)
    const float* __restrict__ Tm,         // (B,3)
    const float* __restrict__ fm,         // (B,2)
    const float* __restrict__ cm,         // (B,2)
    const float* __restrict__ iw_,        // (B,)
    const float* __restrict__ ih_,        // (B,)
    const float* __restrict__ ws,         // coef table (scalar-path reads)
    float* __restrict__ out)              // (B,NP,NJ,ND)
{
    const int b    = blockIdx.x >> 6;     // 64 blocks/batch: 32 pp x 2 dh
    const int rem  = blockIdx.x & 63;
    const int pp   = rem >> 1;
    const int dh   = rem & 1;
    const int p0   = pp * 2;
    const int tid  = threadIdx.x;
    const int lane = tid & 63;
    const int d    = dh * 64 + lane;      // this thread's depth bin
    const int wvs  = __builtin_amdgcn_readfirstlane(tid >> 6);   // 0..3

    __shared__ float4 sq[NPERS][NJOINT];  // {vis, rx, ry, _}  (epilogue)
    __shared__ float  bvred[4][2][64];    // [slice][person][lane]
    __shared__ int    bqred[4][2][64];

    // ---- stage raw candidate data (needed only after the barrier) ----
    for (int i = tid; i < NPERS * NJOINT; i += 256) {
        int q = i / NJOINT, j = i % NJOINT;
        float v  = vis[(b * NPERS + q) * NJOINT + j];
        float rx = p2d[((b * NPERS + q) * NJOINT + j) * 2 + 0];
        float ry = p2d[((b * NPERS + q) * NJOINT + j) * 2 + 1];
        sq[q][j] = make_float4(v, rx, ry, 0.0f);
    }
    // NO barrier here: sq is first read after the post-argmin barrier.

    // ---- camera params (wave-uniform scalars) ----
    const float R00 = Rm[b*9+0], R01 = Rm[b*9+1], R02 = Rm[b*9+2];
    const float R10 = Rm[b*9+3], R11 = Rm[b*9+4], R12 = Rm[b*9+5];
    const float R20 = Rm[b*9+6], R21 = Rm[b*9+7], R22 = Rm[b*9+8];
    const float T0 = Tm[b*3+0], T1 = Tm[b*3+1], T2 = Tm[b*3+2];
    const float fx = fm[b*2+0], fy = fm[b*2+1];
    const float cx = cm[b*2+0], cy = cm[b*2+1];
    const float iwm1 = iw_[b] - 1.0f;
    const float ihm1 = ih_[b] - 1.0f;
    const int   npv  = nper[b];

    const int q0  = wvs * 16;
    const int nvs = __builtin_amdgcn_readfirstlane(
                        min(max(npv - q0, 0), 16));

    const float* pA = poses_3d +
        ((size_t)(b * NPERS + p0    ) * NJOINT * NDEPTH + d) * 3;
    const float* pB = poses_3d +
        ((size_t)(b * NPERS + p0 + 1) * NJOINT * NDEPTH + d) * 3;

    // coef base for this batch: ALL indices below are scalar -> s_load path
    const float* gcb = ws + (size_t)b * NJOINT * 192;
    const float* gcc = ws + (size_t)16 * NJOINT * 192 + b * NPERS;

    float acc0[16], acc1[16];
    #pragma unroll
    for (int k = 0; k < 16; ++k) { acc0[k] = 0.0f; acc1[k] = 0.0f; }

    // one j-step: project both persons, then accumulate GCOUNT 4-q groups.
    // coef reads: uniform float4 from global -> s_load_dwordx4 (scalar).
#define JSTEP(J, GCOUNT)                                                      \
    {                                                                         \
        const int off = (J) * NDEPTH * 3;                                     \
        float X0, Y0, X1, Y1;                                                 \
        {                                                                     \
            float a0 = pA[off + 0] - T0;                                      \
            float a1 = pA[off + 1] - T1;                                      \
            float a2 = pA[off + 2] - T2;                                      \
            float xc0 = R00 * a0 + R01 * a1 + R02 * a2;                       \
            float xc1 = R10 * a0 + R11 * a1 + R12 * a2;                       \
            float xc2 = R20 * a0 + R21 * a1 + R22 * a2;                       \
            float r   = __builtin_amdgcn_rcpf(xc2);                           \
            X0 = fmaf(fx * xc0, r, cx);                                       \
            Y0 = fmaf(fy * xc1, r, cy);                                       \
        }                                                                     \
        {                                                                     \
            float a0 = pB[off + 0] - T0;                                      \
            float a1 = pB[off + 1] - T1;                                      \
            float a2 = pB[off + 2] - T2;                                      \
            float xc0 = R00 * a0 + R01 * a1 + R02 * a2;                       \
            float xc1 = R10 * a0 + R11 * a1 + R12 * a2;                       \
            float xc2 = R20 * a0 + R21 * a1 + R22 * a2;                       \
            float r   = __builtin_amdgcn_rcpf(xc2);                           \
            X1 = fmaf(fx * xc0, r, cx);                                       \
            Y1 = fmaf(fy * xc1, r, cy);                                       \
        }                                                                     \
        const float4* cb4 = (const float4*)(gcb + (J) * 192 + wvs * 48);      \
        _Pragma("unroll")                                                     \
        for (int g = 0; g < (GCOUNT); ++g) {                                  \
            float4 r0 = cb4[g * 3 + 0];                                       \
            float4 r1 = cb4[g * 3 + 1];                                       \
            float4 r2 = cb4[g * 3 + 2];                                       \
            ACC1(0, r0.x, r0.y, r0.z)                                         \
            ACC1(1, r0.w, r1.x, r1.y)                                         \
            ACC1(2, r1.z, r1.w, r2.x)                                         \
            ACC1(3, r2.y, r2.z, r2.w)                                         \
        }                                                                     \
    }

#define ACC1(K, W, WX, WY)                                                    \
    {                                                                         \
        float u;                                                              \
        u = fmaf((W), X0, -(WX));                                             \
        acc0[g * 4 + K] = fmaf(X0, u, acc0[g * 4 + K]);                       \
        u = fmaf((W), Y0, -(WY));                                             \
        acc0[g * 4 + K] = fmaf(Y0, u, acc0[g * 4 + K]);                       \
        u = fmaf((W), X1, -(WX));                                             \
        acc1[g * 4 + K] = fmaf(X1, u, acc1[g * 4 + K]);                       \
        u = fmaf((W), Y1, -(WY));                                             \
        acc1[g * 4 + K] = fmaf(Y1, u, acc1[g * 4 + K]);                       \
    }

    if (nvs == 16) {
        // ---- FAST PATH (critical-path blocks): branch-free, unroll 2 ----
        #pragma unroll 2
        for (int j = 0; j < NJOINT; ++j) {
            JSTEP(j, 4)
        }
    } else if (nvs > 0) {
        // ---- partial slice: off the critical path ----
        #pragma unroll 1
        for (int j = 0; j < NJOINT; ++j) {
            const int ng = (nvs + 3) >> 2;            // scalar 1..4
            if (ng == 4)      { JSTEP(j, 4) }
            else if (ng == 3) { JSTEP(j, 3) }
            else if (ng == 2) { JSTEP(j, 2) }
            else              { JSTEP(j, 1) }
        }
    }
#undef ACC1
#undef JSTEP

    // ---- per-wave argmin (init == np.argmin over BIG-clamped array) ----
    float bv0, bv1;
    int   bq0, bq1;
    if (npv < NPERS) { bv0 = bv1 = BIGF; bq0 = bq1 = npv; }
    else             { bv0 = bv1 = INFF; bq0 = bq1 = 0;   }
    #pragma unroll
    for (int k = 0; k < 16; ++k) {
        if (k < nvs) {                     // scalar branch; gcc[] -> s_load
            float cterm = gcc[q0 + k];
            float d0 = acc0[k] + cterm;
            float d1 = acc1[k] + cterm;
            if (d0 < bv0) { bv0 = d0; bq0 = q0 + k; }
            if (d1 < bv1) { bv1 = d1; bq1 = q0 + k; }
        }
    }
    bvred[wvs][0][lane] = bv0;  bqred[wvs][0][lane] = bq0;
    bvred[wvs][1][lane] = bv1;  bqred[wvs][1][lane] = bq1;
    __syncthreads();                       // guards sq AND bvred/bqred

    // ---- epilogue split over ALL 4 waves: wave = person*2 + j-parity ----
#define EPILOGUE(PI, PAR, PPTR)                                               \
    if (wvs == (PI) * 2 + (PAR)) {                                            \
        float bestv = bvred[0][PI][lane];                                     \
        int   bestq = bqred[0][PI][lane];                                     \
        _Pragma("unroll")                                                     \
        for (int k = 1; k < 4; ++k) {                                         \
            float v  = bvred[k][PI][lane];                                    \
            int   qq = bqred[k][PI][lane];                                    \
            if (v < bestv || (v == bestv && qq < bestq)) {                    \
                bestv = v; bestq = qq;                                        \
            }                                                                 \
        }                                                                     \
        const int obase = ((b * NPERS + p0 + PI) * NJOINT) * NDEPTH + d;      \
        _Pragma("unroll")                                                     \
        for (int j = (PAR); j < NJOINT; j += 2) {                             \
            const int off = j * NDEPTH * 3;                                   \
            float a0 = PPTR[off + 0] - T0;                                    \
            float a1 = PPTR[off + 1] - T1;                                    \
            float a2 = PPTR[off + 2] - T2;                                    \
            float xc0 = R00 * a0 + R01 * a1 + R02 * a2;                       \
            float xc1 = R10 * a0 + R11 * a1 + R12 * a2;                       \
            float xc2 = R20 * a0 + R21 * a1 + R22 * a2;                       \
            float r   = __builtin_amdgcn_rcpf(xc2);                           \
            float xx  = fmaf(fx * xc0, r, cx);                                \
            float yy  = fmaf(fy * xc1, r, cy);                                \
            float4 v = sq[bestq][j];                                          \
            float dx = xx - v.y;                                              \
            float dy = yy - v.z;                                              \
            float md = fmaf(dx, dx, dy * dy);                                 \
            float sc = __expf(-md * (1.0f / 225.0f));                         \
            float inb = (xx >= 0.0f && yy >= 0.0f &&                          \
                         xx <= iwm1 && yy <= ihm1) ? 1.0f : 0.0f;             \
            out[obase + j * NDEPTH] = sc * inb * v.x;                         \
        }                                                                     \
    }

    EPILOGUE(0, 0, pA)
    EPILOGUE(0, 1, pA)
    EPILOGUE(1, 0, pB)
    EPILOGUE(1, 1, pB)
#undef EPILOGUE
}

extern "C" void kernel_launch(void* const* d_in, const int* in_sizes, int n_in,
                              void* d_out, int out_size, void* d_ws, size_t ws_size,
                              hipStream_t stream) {
    const float* poses_3d = (const float*)d_in[0];
    const float* p2d      = (const float*)d_in[1];
    const float* vis      = (const float*)d_in[2];
    const int*   nper     = (const int*)d_in[3];
    const float* Rm       = (const float*)d_in[4];
    const float* Tm       = (const float*)d_in[5];
    const float* fm       = (const float*)d_in[6];
    const float* cm       = (const float*)d_in[7];
    const float* iw       = (const float*)d_in[8];
    const float* ih       = (const float*)d_in[9];
    float* out = (float*)d_out;
    float* ws  = (float*)d_ws;   // B*15*192 + B*64 floats ~= 188 KB

    const int B = in_sizes[3];  // num_persons_ref has B elements
    const int total = B * NPERS;

    coef_kernel<<<(total + 255) / 256, 256, 0, stream>>>(p2d, vis, ws, total);

    dim3 grid(B * 64);          // (b, person-pair, depth-half)
    dim3 block(256);            // 4 waves = 4 contiguous q-slices
    pose_match_kernel<<<grid, block, 0, stream>>>(
        poses_3d, p2d, vis, nper, Rm, Tm, fm, cm, iw, ih, ws, out);
}